// Round 9
// baseline (234.452 us; speedup 1.0000x reference)
//
#include <hip/hip_runtime.h>

#define KK 49
#define BLK 256
#define PPW 16                 // pixels per wave (TPP=4)
#define PPB 64                 // pixels per block (4 waves)
#define WFL (PPW * KK)         // floats per wave slice = 784
#define WF4 (WFL / 4)          // float4 per wave slice = 196

// Catmull-Rom a=-0.5 via range-selected Horner, 9 VALU ops:
//   t = min(|x|,2);  s = t<1
//   P1 = 1.5t^3 - 2.5t^2 + 1        (s)
//   P2 = -0.5t^3 + 2.5t^2 - 4t + 2  (!s; P2(2)=0 handles |x|>=2 exactly)
static __device__ __forceinline__ float cubicH(float x) {
    const float t  = __builtin_fminf(__builtin_fabsf(x), 2.0f);
    const bool  s  = t < 1.0f;
    const float c3 = s ?  1.5f : -0.5f;
    const float c2 = s ? -2.5f :  2.5f;
    const float c1 = s ?  0.0f : -4.0f;
    const float c0 = s ?  1.0f :  2.0f;
    return __builtin_fmaf(__builtin_fmaf(__builtin_fmaf(c3, t, c2), t, c1), t, c0);
}

// TPP=4: 4 lanes per pixel, 12-13 taps each.  LDS slice halves vs TPP=2 ->
// 12544 B/block -> 8 blocks/CU (thread-capped) = 32 waves/CU = 100% occupancy
// (R6 measured 60% at the old 25088 B).  (256,8) pins VGPR <= 64.
__global__ __launch_bounds__(BLK, 8) void kest_kernel(
    const float* __restrict__ m,
    const float* __restrict__ grid,
    const int*   __restrict__ Wp,
    const int*   __restrict__ yi,
    float*       __restrict__ out,
    int N)
{
    __shared__ __align__(16) float lds[4 * WFL];   // 12544 B

    const int tid   = threadIdx.x;
    const int wv_   = tid >> 6;          // wave id 0..3
    const int lane  = tid & 63;
    const int pixW  = lane >> 2;         // pixel-in-wave 0..15
    const int sub   = lane & 3;          // tap phase 0..3
    const int blockBase = blockIdx.x * PPB;
    float* ldsW = &lds[wv_ * WFL];       // wave-private slice: NO barrier needed

    const int i = blockBase + wv_ * PPW + pixW;   // this lane's pixel

    if (i < N) {
        // ---- setup: all 64 lanes, 4x redundant per pixel (no exec-mask idle,
        // no broadcast shuffles; loads L1-broadcast).  R4 showed ~neutral. ----
        const float m00 = m[0], m01 = m[1], m02 = m[2];
        const float m10 = m[3], m11 = m[4], m12 = m[5];
        const float m20 = m[6], m21 = m[7], m22 = m[8];
        const int   W   = Wp[0];

        const int j = yi[i];
        int yyI, xxI;
        if ((W & (W - 1)) == 0) {            // uniform branch (W=1024)
            yyI = j >> (__ffs(W) - 1);
            xxI = j & (W - 1);
        } else {
            yyI = j / W;
            xxI = j - yyI * W;
        }
        const float xx = (float)xxI, yy = (float)yyI;

        const float X0 = m00 * xx + m01 * yy + m02;
        const float Y0 = m10 * xx + m11 * yy + m12;
        const float Z0 = m20 * xx + m21 * yy + m22;

        // stable difference-of-quotients: du (eps_y=±0.5), dv (eps_x=±0.5)
        const float izy = __builtin_amdgcn_rcpf(Z0 * Z0 - 0.25f * m21 * m21);
        float du0 = (m01 * Z0 - m21 * X0) * izy;
        float du1 = (m11 * Z0 - m21 * Y0) * izy;
        const float izx = __builtin_amdgcn_rcpf(Z0 * Z0 - 0.25f * m20 * m20);
        float dv0 = (m00 * Z0 - m20 * X0) * izx;
        float dv1 = (m10 * Z0 - m20 * Y0) * izx;

        const float d2u = du0 * du0 + du1 * du1;
        const float rlu = __builtin_amdgcn_rsqf(d2u);
        float len_du = d2u * rlu;
        if (len_du < 1.0f) { du0 *= rlu; du1 *= rlu; len_du = 1.0f; }
        const float d2v = dv0 * dv0 + dv1 * dv1;
        const float rlv = __builtin_amdgcn_rsqf(d2v);
        float len_dv = d2v * rlv;
        if (len_dv < 1.0f) { dv0 *= rlv; dv1 *= rlv; len_dv = 1.0f; }

        const float det  = du0 * dv1 - du1 * dv0;
        const float r_du = __builtin_amdgcn_rcpf(len_du * det);
        const float r_dv = __builtin_amdgcn_rcpf(len_dv * det);

        const float p1 = du0 * dv1, p2 = du1 * dv0;
        const float Axx = p1 * r_du - p2 * r_dv;
        const float Axy = du0 * du1 * (r_dv - r_du);
        const float Ayx = dv0 * dv1 * (r_du - r_dv);
        const float Ayy = p1 * r_dv - p2 * r_du;

        const float px = grid[i]     + 0.5f;
        const float py = grid[N + i] + 0.5f;
        const float fxc = (px - __builtin_floorf(px)) + 2.5f;
        const float fyc = (py - __builtin_floorf(py)) + 2.5f;

        // ---- per-lane tap tables.  Lane handles q = 4j + sub, j = 0..12.
        // c = (4j)%7, a = (4j)/7 compile-time; cond = (sub >= 7-c) runtime.
        //   wx = fxc - cx(q) = cond ? ux[c] : ux[c+7]   (ux[k] = g - (k-7))
        //   wy = fyc - ry(q) = cond ? vy[a+1] : vy[a]   (vy[a] = fyc - a)
        // cond is compile-time FALSE for c<=3 (sub<=3), so only c in {4,5,6}
        // taps (6 of 13) pay the two cndmasks.  All indices compile-time.
        const float g = fxc - (float)sub;
        float ux[14];
#pragma unroll
        for (int k = 0; k < 14; ++k) ux[k] = g - (float)(k - 7);
        float vy[8];
#pragma unroll
        for (int a = 0; a < 8; ++a) vy[a] = fyc - (float)a;

        float w[13];
        float ws = 0.0f;
#pragma unroll
        for (int jj = 0; jj < 13; ++jj) {
            const int qb = 4 * jj;
            const int c  = qb % 7, a = qb / 7;
            const bool cond = (sub >= 7 - c);      // folds to false for c<=3
            const float wx = cond ? ux[c]     : ux[c + 7];
            const float wy = cond ? vy[a + 1] : vy[a];
            const float x_ = __builtin_fmaf(Axx, wx, Axy * wy);
            const float y_ = __builtin_fmaf(Ayx, wx, Ayy * wy);
            float wt = cubicH(x_) * cubicH(y_);
            if (jj == 12) wt = (sub == 0) ? wt : 0.0f;  // q=49..51 invalid
            w[jj] = wt;
            ws += wt;
        }
        // combine the pixel's 4 lanes (uniform validity per 4-group -> convergent)
        ws += __shfl_xor(ws, 1);
        ws += __shfl_xor(ws, 2);
        const float rs = __builtin_amdgcn_rcpf(ws);

        // LDS write: addr = pixW*49 + 4j + sub; bank = (17*pixW + sub + 4j)%32
        // -> exactly 2 lanes/bank (free, m136)
        float* base = &ldsW[pixW * KK + sub];
#pragma unroll
        for (int jj = 0; jj < 13; ++jj) {
            if (jj < 12) {
                base[4 * jj] = w[jj] * rs;
            } else if (sub == 0) {
                base[48] = w[12] * rs;         // q=48 only; q>=49 would corrupt
            }
        }
    }

    // ---- wave-private drain, no barrier: compiler's lgkmcnt wait suffices ----
    const long long dstF4 = (long long)blockIdx.x * (PPB * KK / 4) + wv_ * WF4;
    if (blockBase + PPB <= N) {            // uniform fast path: block fully valid
        const float4* src = (const float4*)ldsW;
        float4* dst = (float4*)out + dstF4;
#pragma unroll
        for (int k = 0; k < 4; ++k) {
            const int t = lane + 64 * k;
            if (t < WF4) dst[t] = src[t];  // k<3 always; k=3: lanes 0..3
        }
    } else {                               // tail block: scalar, bounds-checked
        const float* s = (const float*)ldsW;
        const long long baseF = dstF4 * 4;
        const long long limF  = (long long)N * KK;
        for (int t = lane; t < WFL; t += 64)
            if (baseF + t < limF) out[baseF + t] = s[t];
    }
}

extern "C" void kernel_launch(void* const* d_in, const int* in_sizes, int n_in,
                              void* d_out, int out_size, void* d_ws, size_t ws_size,
                              hipStream_t stream) {
    // inputs: m_inverse(9 f32), grid(2N f32), H(1 i32), W(1 i32), yi(N i32)
    const float* m    = (const float*)d_in[0];
    const float* grid = (const float*)d_in[1];
    const int*   Wp   = (const int*)d_in[3];
    const int*   yi   = (const int*)d_in[4];
    float*       out  = (float*)d_out;
    const int N = in_sizes[4];

    const int blocks = (N + PPB - 1) / PPB;
    kest_kernel<<<blocks, BLK, 0, stream>>>(m, grid, Wp, yi, out, N);
}